// Round 1
// baseline (3885.197 us; speedup 1.0000x reference)
//
#include <hip/hip_runtime.h>

// ConvLSTM2D x2 encoder, fp32 baseline.
// B=8, T=10, H=W=64, Cin=1, F=64, 4F=256 gates, 3x3 SAME conv.
// Layers interleaved per timestep: L0(t) then L1(t); only ping-pong state in ws.

#define HWF (64 * 64 * 64)   // elems per batch image of [H,W,F]

__device__ __forceinline__ float hsig(float x) {
    return fminf(fmaxf(fmaf(0.2f, x, 0.5f), 0.0f), 1.0f);
}

// Stage a 10x10 halo tile of a [H=64,W=64,C=64] channel-last image into LDS,
// channel-planar: tile[c*100 + r*10 + col]. Zero-pad out-of-bounds.
__device__ __forceinline__ void stage_tile64(const float* __restrict__ src,
                                             float* __restrict__ tile,
                                             int y0, int x0, int tid) {
    const float4* src4 = (const float4*)src;
    for (int v = tid; v < 1600; v += 256) {
        int cell = v >> 4;          // 0..99
        int j    = v & 15;          // float4 index within 64 channels
        int r  = cell / 10, cc = cell - r * 10;
        int y  = y0 - 1 + r,  x  = x0 - 1 + cc;
        float4 f = make_float4(0.f, 0.f, 0.f, 0.f);
        if ((unsigned)y < 64u && (unsigned)x < 64u)
            f = src4[(size_t)((y << 6) + x) * 16 + j];
        tile[(j * 4 + 0) * 100 + cell] = f.x;
        tile[(j * 4 + 1) * 100 + cell] = f.y;
        tile[(j * 4 + 2) * 100 + cell] = f.z;
        tile[(j * 4 + 3) * 100 + cell] = f.w;
    }
}

__device__ __forceinline__ void fma_block(float acc[4][16], const float in_[4],
                                          const float w[16]) {
    #pragma unroll
    for (int i = 0; i < 4; ++i)
        #pragma unroll
        for (int k = 0; k < 16; ++k)
            acc[i][k] = fmaf(in_[i], w[k], acc[i][k]);
}

// 3x3 conv over 64 input channels; W layout [3,3,64,256] channel-last.
// Thread accumulates 4 positions x (4 gates x 4 f-channels), n = g*64 + q*4 + k.
__device__ __forceinline__ void conv64(const float* __restrict__ Wg,
                                       const float* __restrict__ tile,
                                       const int pc[4], int q, float acc[4][16]) {
    const float4* W4 = (const float4*)Wg;
    #pragma unroll
    for (int tap = 0; tap < 9; ++tap) {
        const int off = (tap / 3) * 10 + (tap % 3);
        const float4* Wt = W4 + tap * 4096 + q;   // (tap*64+c)*64 + g*16 + q
        #pragma unroll 2
        for (int c = 0; c < 64; ++c) {
            const float* tc = tile + c * 100 + off;
            float in_[4] = { tc[pc[0]], tc[pc[1]], tc[pc[2]], tc[pc[3]] };
            float4 w0 = Wt[c * 64];
            float4 w1 = Wt[c * 64 + 16];
            float4 w2 = Wt[c * 64 + 32];
            float4 w3 = Wt[c * 64 + 48];
            float w[16] = { w0.x, w0.y, w0.z, w0.w,  w1.x, w1.y, w1.z, w1.w,
                            w2.x, w2.y, w2.z, w2.w,  w3.x, w3.y, w3.z, w3.w };
            fma_block(acc, in_, w);
        }
    }
}

template <int CIN>
__global__ __launch_bounds__(256, 2) void step_kernel(
    const float* __restrict__ in, int in_bstride,
    const float* __restrict__ h_in,    // null at t==0 (treated as zeros)
    const float* __restrict__ c_in,    // null at t==0
    const float* __restrict__ Wx, const float* __restrict__ Wh,
    const float* __restrict__ bias,
    float* __restrict__ h_out, float* __restrict__ c_out,
    float* __restrict__ h_out2, float* __restrict__ c_out2)  // extra copy at t==T-1
{
    __shared__ float tile[6400];  // 64 planes x 100 (10x10 halo tile)
    const int tid = threadIdx.x;
    const int b  = blockIdx.z;
    const int x0 = blockIdx.x * 8, y0 = blockIdx.y * 8;
    const int q  = tid & 15;      // f-channel quad: fc = q*4..q*4+3
    const int pg = tid >> 4;
    const int p0 = pg * 4;        // 4 consecutive positions in 8x8 tile
    int pc[4];
    #pragma unroll
    for (int i = 0; i < 4; ++i) {
        int p = p0 + i;
        pc[i] = (p >> 3) * 10 + (p & 7);
    }

    // init accumulators with bias; acc[i][g*4+k] is gate g, f-channel q*4+k
    float acc[4][16];
    const float4* b4 = (const float4*)bias;
    #pragma unroll
    for (int g = 0; g < 4; ++g) {
        float4 bv = b4[g * 16 + q];
        #pragma unroll
        for (int i = 0; i < 4; ++i) {
            acc[i][g * 4 + 0] = bv.x;
            acc[i][g * 4 + 1] = bv.y;
            acc[i][g * 4 + 2] = bv.z;
            acc[i][g * 4 + 3] = bv.w;
        }
    }

    // ---- input-to-gate conv ----
    if (CIN == 1) {
        const float* src = in + (size_t)b * in_bstride;
        for (int v = tid; v < 100; v += 256) {
            int r = v / 10, cc = v - r * 10;
            int y = y0 - 1 + r, x = x0 - 1 + cc;
            tile[v] = ((unsigned)y < 64u && (unsigned)x < 64u) ? src[(y << 6) + x] : 0.f;
        }
        __syncthreads();
        const float4* Wx4 = (const float4*)Wx;   // [3,3,1,256]
        #pragma unroll
        for (int tap = 0; tap < 9; ++tap) {
            const int off = (tap / 3) * 10 + (tap % 3);
            float4 w0 = Wx4[tap * 64 + q];
            float4 w1 = Wx4[tap * 64 + 16 + q];
            float4 w2 = Wx4[tap * 64 + 32 + q];
            float4 w3 = Wx4[tap * 64 + 48 + q];
            float w[16] = { w0.x, w0.y, w0.z, w0.w,  w1.x, w1.y, w1.z, w1.w,
                            w2.x, w2.y, w2.z, w2.w,  w3.x, w3.y, w3.z, w3.w };
            float in_[4] = { tile[pc[0] + off], tile[pc[1] + off],
                             tile[pc[2] + off], tile[pc[3] + off] };
            fma_block(acc, in_, w);
        }
    } else {
        stage_tile64(in + (size_t)b * in_bstride, tile, y0, x0, tid);
        __syncthreads();
        conv64(Wx, tile, pc, q, acc);
    }

    // ---- recurrent conv ----
    if (h_in) {
        __syncthreads();
        stage_tile64(h_in + (size_t)b * HWF, tile, y0, x0, tid);
        __syncthreads();
        conv64(Wh, tile, pc, q, acc);
    }

    // ---- LSTM pointwise epilogue (thread-local: owns all 4 gates) ----
    #pragma unroll
    for (int i = 0; i < 4; ++i) {
        int p = p0 + i;
        int py = p >> 3, px = p & 7;
        size_t s   = (size_t)((y0 + py) << 6) + (x0 + px);
        size_t idx = (size_t)b * (HWF / 4) + s * 16 + q;   // float4 index
        float4 cp = make_float4(0.f, 0.f, 0.f, 0.f);
        if (c_in) cp = ((const float4*)c_in)[idx];
        float iv[4], fv[4], gv[4], ov[4];
        #pragma unroll
        for (int k = 0; k < 4; ++k) {
            iv[k] = hsig(acc[i][k]);
            fv[k] = hsig(acc[i][4 + k]);
            gv[k] = tanhf(acc[i][8 + k]);
            ov[k] = hsig(acc[i][12 + k]);
        }
        float4 cn, hn;
        cn.x = fmaf(fv[0], cp.x, iv[0] * gv[0]);
        cn.y = fmaf(fv[1], cp.y, iv[1] * gv[1]);
        cn.z = fmaf(fv[2], cp.z, iv[2] * gv[2]);
        cn.w = fmaf(fv[3], cp.w, iv[3] * gv[3]);
        hn.x = ov[0] * tanhf(cn.x);
        hn.y = ov[1] * tanhf(cn.y);
        hn.z = ov[2] * tanhf(cn.z);
        hn.w = ov[3] * tanhf(cn.w);
        ((float4*)c_out)[idx] = cn;
        ((float4*)h_out)[idx] = hn;
        if (h_out2) {
            ((float4*)h_out2)[idx] = hn;
            ((float4*)c_out2)[idx] = cn;
        }
    }
}

extern "C" void kernel_launch(void* const* d_in, const int* in_sizes, int n_in,
                              void* d_out, int out_size, void* d_ws, size_t ws_size,
                              hipStream_t stream) {
    const float* x   = (const float*)d_in[0];   // [8,10,64,64,1]
    const float* Wx0 = (const float*)d_in[1];   // [3,3,1,256]
    const float* Wh0 = (const float*)d_in[2];   // [3,3,64,256]
    const float* b0  = (const float*)d_in[3];   // [256]
    const float* Wx1 = (const float*)d_in[4];   // [3,3,64,256]
    const float* Wh1 = (const float*)d_in[5];   // [3,3,64,256]
    const float* b1  = (const float*)d_in[6];   // [256]
    float* out = (float*)d_out;                 // [2,2,8,64,64,64]
    float* ws  = (float*)d_ws;

    const size_t BHWF = (size_t)8 * HWF;        // 2,097,152 floats
    float* h0buf[2] = { ws, ws + BHWF };
    float* c0 = ws + 2 * BHWF;
    float* h1buf[2] = { ws + 3 * BHWF, ws + 4 * BHWF };
    float* c1 = ws + 5 * BHWF;

    dim3 grid(8, 8, 8), block(256);
    for (int t = 0; t < 10; ++t) {
        const int cur = t & 1, prv = cur ^ 1;
        const bool last = (t == 9);
        // Layer 0: input x[:,t] (Cin=1), recurrent on h0
        step_kernel<1><<<grid, block, 0, stream>>>(
            x + (size_t)t * 4096, 40960,
            t ? h0buf[prv] : nullptr, t ? c0 : nullptr,
            Wx0, Wh0, b0,
            h0buf[cur], c0,
            last ? out : nullptr, last ? out + BHWF : nullptr);
        // Layer 1: input = h0(t) (Cin=64), recurrent on h1
        step_kernel<64><<<grid, block, 0, stream>>>(
            h0buf[cur], HWF,
            t ? h1buf[prv] : nullptr, t ? c1 : nullptr,
            Wx1, Wh1, b1,
            h1buf[cur], c1,
            last ? out + 2 * BHWF : nullptr, last ? out + 3 * BHWF : nullptr);
    }
}

// Round 2
// 756.078 us; speedup vs baseline: 5.1386x; 5.1386x over previous
//
#include <hip/hip_runtime.h>

// ConvLSTM2D x2 encoder — bf16 MFMA implicit-GEMM version.
// B=8, T=10, H=W=64, Cin=1, F=64, 4F=256 gates, 3x3 SAME conv.
// Per conv step: GEMM M=positions, N=256 gates, K=576 (9 taps x 64 ch).
// 256 blocks (b=8 x 8 row-tiles x 4 col-tiles of 8x16 positions), 512 thr = 8 waves.
// Wave (mh,fq): M=64 (4 spatial rows) x N=64 (16 f-channels x 4 gates),
// 4x4 tiles of mfma_f32_16x16x32_bf16. c-state kept fp32; h stored bf16.

typedef __bf16 bf16x8 __attribute__((ext_vector_type(8)));
typedef float f32x4 __attribute__((ext_vector_type(4)));

#define BHWF (8 * 64 * 64 * 64)   // 2,097,152 elems per state tensor
#define TSTRIDE 72                // LDS tile channel stride (bf16 units)

__device__ __forceinline__ float hsig(float x) {
    return fminf(fmaxf(fmaf(0.2f, x, 0.5f), 0.0f), 1.0f);
}

__device__ __forceinline__ ushort f2bf(float f) {
    unsigned u = __float_as_uint(f);
    unsigned r = (u + 0x7FFFu + ((u >> 16) & 1u)) >> 16;
    return (ushort)r;
}

// Transpose+convert [576][256] fp32 -> [256][576] bf16.  grid(576,3) x 256.
__global__ void prep_w(const float* __restrict__ s0, const float* __restrict__ s1,
                       const float* __restrict__ s2,
                       ushort* __restrict__ d0, ushort* __restrict__ d1,
                       ushort* __restrict__ d2) {
    const float* s[3] = { s0, s1, s2 };
    ushort* d[3] = { d0, d1, d2 };
    int which = blockIdx.y;
    int i = blockIdx.x * 256 + threadIdx.x;
    if (i < 576 * 256) {
        int n = i / 576, k = i - n * 576;
        d[which][i] = f2bf(s[which][k * 256 + n]);
    }
}

// Stage 10x18 halo tile of bf16 [4096][64] image into LDS [cell][TSTRIDE].
__device__ __forceinline__ void stage(const ushort* __restrict__ src,
                                      ushort* __restrict__ tile,
                                      int y0, int x0, int tid) {
    for (int v = tid; v < 1440; v += 512) {
        int cell = v >> 3, j = v & 7;
        int r = cell / 18, cc = cell - r * 18;
        int y = y0 - 1 + r, xx = x0 - 1 + cc;
        uint4 dv = make_uint4(0u, 0u, 0u, 0u);
        if ((unsigned)y < 64u && (unsigned)xx < 64u)
            dv = ((const uint4*)src)[(size_t)((y << 6) + xx) * 8 + j];
        *(uint4*)&tile[cell * TSTRIDE + j * 8] = dv;
    }
}

__device__ __forceinline__ void conv_mfma(const ushort* __restrict__ tile,
                                          const ushort* __restrict__ WT,
                                          f32x4 (&acc)[4][4],
                                          int mh, int fq, int lane) {
    const int colA = lane & 15;
    const int quad = (lane >> 4) & 3;
    const int fr = fq * 16 + colA;          // f index for B rows
    #pragma unroll
    for (int tap = 0; tap < 9; ++tap) {
        const int dy = tap / 3, dx = tap - dy * 3;
        #pragma unroll
        for (int kc = 0; kc < 2; ++kc) {
            const int kk = tap * 64 + kc * 32 + quad * 8;
            bf16x8 a[4], b[4];
            #pragma unroll
            for (int mt = 0; mt < 4; ++mt) {
                int cell = (mh * 4 + mt + dy) * 18 + (colA + dx);
                a[mt] = *(const bf16x8*)&tile[cell * TSTRIDE + kc * 32 + quad * 8];
            }
            #pragma unroll
            for (int g = 0; g < 4; ++g)
                b[g] = *(const bf16x8*)&WT[(size_t)(g * 64 + fr) * 576 + kk];
            #pragma unroll
            for (int mt = 0; mt < 4; ++mt)
                #pragma unroll
                for (int g = 0; g < 4; ++g)
                    acc[mt][g] = __builtin_amdgcn_mfma_f32_16x16x32_bf16(
                        a[mt], b[g], acc[mt][g], 0, 0, 0);
        }
    }
}

// LAYER 0: x-conv (Cin=1) folded scalar into acc init; recurrent MFMA conv.
// LAYER 1: input conv (on xin, bf16) + recurrent conv, both MFMA.
template <int LAYER>
__global__ __launch_bounds__(512, 2) void step_mfma(
    const float* __restrict__ x,       // L0: fp32 x at timestep t (b-stride 40960)
    const ushort* __restrict__ xin,    // L1: bf16 h0_cur [B][4096][64]
    const ushort* __restrict__ WxT,    // L1: bf16 [256][576]
    const float* __restrict__ Wx0,     // L0: fp32 [9][256]
    const ushort* __restrict__ WhT,    // bf16 [256][576]; null => skip recurrent conv
    const float* __restrict__ bias,    // fp32 [256]
    const ushort* __restrict__ h_prev, // bf16, null at t==0
    const float* __restrict__ c_prev,  // fp32, null at t==0
    ushort* __restrict__ h_out,        // bf16 ws
    float* __restrict__ c_out,         // fp32 ws
    float* __restrict__ h_fout,        // t==9: fp32 d_out region, else null
    float* __restrict__ c_fout)
{
    __shared__ __align__(16) ushort tile[180 * TSTRIDE];
    __shared__ float xtile[180];

    const int tid = threadIdx.x;
    const int lane = tid & 63;
    const int w = tid >> 6;
    const int mh = w & 1;               // m half: rows 0-3 or 4-7
    const int fq = w >> 1;              // f quad: f base = fq*16
    const int colA = lane & 15;
    const int quad = (lane >> 4) & 3;
    const int b = blockIdx.z;
    const int x0 = blockIdx.x * 16, y0 = blockIdx.y * 8;
    const int f = fq * 16 + colA;

    // ---- stage first A tile ----
    if (LAYER == 0) {
        const float* xs = x + (size_t)b * 40960;
        for (int v = tid; v < 180; v += 512) {
            int r = v / 18, cc = v - r * 18;
            int y = y0 - 1 + r, xx = x0 - 1 + cc;
            xtile[v] = ((unsigned)y < 64u && (unsigned)xx < 64u) ? xs[(y << 6) + xx] : 0.f;
        }
        if (h_prev) stage(h_prev + (size_t)b * 4096 * 64, tile, y0, x0, tid);
    } else {
        stage(xin + (size_t)b * 4096 * 64, tile, y0, x0, tid);
    }
    __syncthreads();

    // ---- init accumulators: bias (+ scalar x-conv for L0) ----
    f32x4 acc[4][4];
    #pragma unroll
    for (int g = 0; g < 4; ++g) {
        float bv = bias[g * 64 + f];
        #pragma unroll
        for (int mt = 0; mt < 4; ++mt) {
            acc[mt][g][0] = bv; acc[mt][g][1] = bv;
            acc[mt][g][2] = bv; acc[mt][g][3] = bv;
        }
    }
    if (LAYER == 0) {
        float wx[9][4];
        #pragma unroll
        for (int tap = 0; tap < 9; ++tap)
            #pragma unroll
            for (int g = 0; g < 4; ++g)
                wx[tap][g] = Wx0[tap * 256 + g * 64 + f];
        #pragma unroll
        for (int mt = 0; mt < 4; ++mt) {
            const int rr = mh * 4 + mt;
            #pragma unroll
            for (int reg = 0; reg < 4; ++reg) {
                const int cc = quad * 4 + reg;
                float s0 = 0.f, s1 = 0.f, s2 = 0.f, s3 = 0.f;
                #pragma unroll
                for (int tap = 0; tap < 9; ++tap) {
                    int dy = tap / 3, dx = tap - dy * 3;
                    float xv = xtile[(rr + dy) * 18 + cc + dx];
                    s0 = fmaf(xv, wx[tap][0], s0);
                    s1 = fmaf(xv, wx[tap][1], s1);
                    s2 = fmaf(xv, wx[tap][2], s2);
                    s3 = fmaf(xv, wx[tap][3], s3);
                }
                acc[0 + mt][0][reg] += 0.f;  // keep structure simple
                acc[mt][0][reg] += s0; acc[mt][1][reg] += s1;
                acc[mt][2][reg] += s2; acc[mt][3][reg] += s3;
            }
        }
    }

    // ---- conv 1 ----
    if (LAYER == 0) {
        if (WhT && h_prev) conv_mfma(tile, WhT, acc, mh, fq, lane);
    } else {
        conv_mfma(tile, WxT, acc, mh, fq, lane);
        // ---- conv 2: recurrent ----
        if (h_prev && WhT) {
            __syncthreads();
            stage(h_prev + (size_t)b * 4096 * 64, tile, y0, x0, tid);
            __syncthreads();
            conv_mfma(tile, WhT, acc, mh, fq, lane);
        }
    }

    // ---- LSTM pointwise epilogue ----
    #pragma unroll
    for (int mt = 0; mt < 4; ++mt) {
        const int y = y0 + mh * 4 + mt;
        #pragma unroll
        for (int reg = 0; reg < 4; ++reg) {
            const int xx = x0 + quad * 4 + reg;
            const size_t pidx = ((size_t)b * 4096 + (y << 6) + xx) * 64 + f;
            float cp = c_prev ? c_prev[pidx] : 0.f;
            float iv = hsig(acc[mt][0][reg]);
            float fv = hsig(acc[mt][1][reg]);
            float gv = tanhf(acc[mt][2][reg]);
            float ov = hsig(acc[mt][3][reg]);
            float cn = fmaf(fv, cp, iv * gv);
            float hn = ov * tanhf(cn);
            c_out[pidx] = cn;
            h_out[pidx] = f2bf(hn);
            if (h_fout) { h_fout[pidx] = hn; c_fout[pidx] = cn; }
        }
    }
}

extern "C" void kernel_launch(void* const* d_in, const int* in_sizes, int n_in,
                              void* d_out, int out_size, void* d_ws, size_t ws_size,
                              hipStream_t stream) {
    const float* x   = (const float*)d_in[0];   // [8,10,64,64,1]
    const float* Wx0 = (const float*)d_in[1];   // [3,3,1,256] == [9][256]
    const float* Wh0 = (const float*)d_in[2];   // [3,3,64,256]
    const float* b0  = (const float*)d_in[3];
    const float* Wx1 = (const float*)d_in[4];
    const float* Wh1 = (const float*)d_in[5];
    const float* b1  = (const float*)d_in[6];
    float* out = (float*)d_out;                 // [2,2,8,64,64,64] fp32
    char* ws = (char*)d_ws;

    // ws layout
    ushort* h0buf[2] = { (ushort*)ws, (ushort*)(ws + 4u * 1024 * 1024) };
    ushort* h1buf[2] = { (ushort*)(ws + 8u * 1024 * 1024), (ushort*)(ws + 12u * 1024 * 1024) };
    float* c0 = (float*)(ws + 16u * 1024 * 1024);
    float* c1 = (float*)(ws + 24u * 1024 * 1024);
    ushort* Wh0T = (ushort*)(ws + 32u * 1024 * 1024);
    ushort* Wx1T = Wh0T + 576 * 256;
    ushort* Wh1T = Wx1T + 576 * 256;

    prep_w<<<dim3(576, 3), 256, 0, stream>>>(Wh0, Wx1, Wh1, Wh0T, Wx1T, Wh1T);

    dim3 grid(4, 8, 8), block(512);
    for (int t = 0; t < 10; ++t) {
        const int cur = t & 1, prv = cur ^ 1;
        const bool last = (t == 9);
        step_mfma<0><<<grid, block, 0, stream>>>(
            x + (size_t)t * 4096, nullptr, nullptr, Wx0,
            t ? Wh0T : nullptr, b0,
            t ? h0buf[prv] : nullptr, t ? c0 : nullptr,
            h0buf[cur], c0,
            last ? out : nullptr, last ? out + BHWF : nullptr);
        step_mfma<1><<<grid, block, 0, stream>>>(
            nullptr, h0buf[cur], Wx1T, nullptr,
            Wh1T, b1,
            t ? h1buf[prv] : nullptr, t ? c1 : nullptr,
            h1buf[cur], c1,
            last ? out + 2 * (size_t)BHWF : nullptr, last ? out + 3 * (size_t)BHWF : nullptr);
    }
}